// Round 13
// baseline (138.905 us; speedup 1.0000x reference)
//
#include <hip/hip_runtime.h>

typedef _Float16 f16;
typedef _Float16 f16x8 __attribute__((ext_vector_type(8)));
typedef _Float16 f16x4 __attribute__((ext_vector_type(4)));
typedef float f32x4 __attribute__((ext_vector_type(4)));

__device__ __forceinline__ float rcpf(float x) { return __builtin_amdgcn_rcpf(x); }

// ---------------- kernel 1: weight convert -> FRAGMENT-ORDERED layout ------
// Wt'[(nt*3+w)*8+kt][kq][ni][rl][8 halfs]
__global__ void __launch_bounds__(256) cvt_w(const float* __restrict__ Wr,
                                             const float* __restrict__ Wz,
                                             const float* __restrict__ Wh,
                                             f16* __restrict__ out) {
  int o = blockIdx.x * 256 + threadIdx.x;        // < 49152
  int rl = o & 15, ni = (o >> 4) & 3, kq = (o >> 6) & 3, kt = (o >> 8) & 7;
  int wnt = o >> 11;
  int w = wnt % 3, nt = wnt / 3;
  int n = nt * 64 + ni * 16 + rl;
  int k0 = kt * 32 + kq * 8;
  const float* W = (w == 0) ? Wr : ((w == 1) ? Wz : Wh);
  f16x8 v;
#pragma unroll
  for (int e = 0; e < 8; ++e) v[e] = (f16)W[(size_t)(k0 + e) * 512 + n];
  *(f16x8*)(out + (size_t)o * 8) = v;
}

// ---------------- kernel 2: x convert f32->f16, FRAGMENT-ORDERED -----------
// Xf'[m16*8+kt][kq][rl][8 halfs]
__global__ void __launch_bounds__(256) cvt_x(const float* __restrict__ in,
                                             f16* __restrict__ out) {
  int o = blockIdx.x * 256 + threadIdx.x;        // < 2097152
  int rl = o & 15, kq = (o >> 4) & 3, kt = (o >> 6) & 7, m16 = o >> 9;
  const float* src = in + (size_t)(m16 * 16 + rl) * 256 + kt * 32 + kq * 8;
  f16x8 v;
#pragma unroll
  for (int e = 0; e < 8; ++e) v[e] = (f16)src[e];
  *(f16x8*)(out + (size_t)o * 8) = v;
}

// ---------------- kernel 3: producer/consumer fused GEMM + scan ------------
// Block = (b, hs: 128-h slice), grid 512, 512 threads = 8 waves.
// Waves 0..5 (producers): register-streamed GEMM of t-tile 32 (phase p+1)
//   into LDS P buffer (p+1)&1, with kt-level double-buffered register
//   prefetch (even/odd named frag sets -> ~100 VGPR, loads pipelined).
// Waves 6,7 (consumers): scan 32 t-steps of phase p from buffer p&1.
// One __syncthreads per phase; double-buffered P (49 KB) -> 2 blocks/CU.
__global__ void __launch_bounds__(512, 4) brc_fused(
    const f16* __restrict__ Af, const f16* __restrict__ Bf,
    const float* __restrict__ h0, const float* __restrict__ mr,
    const float* __restrict__ mz, const float* __restrict__ br,
    const float* __restrict__ bz, float* __restrict__ out) {
  __shared__ __align__(16) f16 Pl[2][12288];     // [buf][w3*4096+tg*1024+hl*8+t7]
  const int tid = threadIdx.x;
  const int wid = tid >> 6, lane = tid & 63;
  const int bid = blockIdx.x;
  const int lid = (bid & 7) * 64 + (bid >> 3);   // bijective XCD swizzle
  const int b = lid >> 2, hs = lid & 3;          // 4 hs-blocks of a b adjacent

  // ---- producer constants (waves 0..5) ----
  const int w3 = wid >> 1, hh = wid & 1;
  const int nt = hs * 2 + hh;
  const char* Ap = (const char*)Af + lane * 16;
  const char* Bp = (const char*)Bf + (lane >> 4) * 1024 + (lane & 15) * 16 +
                   (size_t)(nt * 3 + w3) * 32768;
  const int col = lane & 15, rbase = (lane >> 4) * 4;

  // ---- consumer state (waves 6,7): chain c = tid & 127 ----
  const int c = tid & 127;
  const int hg = hs * 128 + c;
  float h = h0[(size_t)b * 512 + hg];
  const float mrc = 2.0f * mr[hg], mzc = -mz[hg];
  const float br2 = 2.0f * br[hg], nbz = -bz[hg];

#define LOADF(A0, A1, B0, B1, B2, B3, q, kt)                                  \
  do {                                                                        \
    A0 = *(const f16x8*)(Ap + (size_t)((b * 32 + (q) * 2 + 0) * 8 + (kt)) * 1024); \
    A1 = *(const f16x8*)(Ap + (size_t)((b * 32 + (q) * 2 + 1) * 8 + (kt)) * 1024); \
    B0 = *(const f16x8*)(Bp + (size_t)(kt) * 4096 + 0 * 256);                 \
    B1 = *(const f16x8*)(Bp + (size_t)(kt) * 4096 + 1 * 256);                 \
    B2 = *(const f16x8*)(Bp + (size_t)(kt) * 4096 + 2 * 256);                 \
    B3 = *(const f16x8*)(Bp + (size_t)(kt) * 4096 + 3 * 256);                 \
  } while (0)

#define MFMA8(A0, A1, B0, B1, B2, B3)                                         \
  do {                                                                        \
    acc[0][0] = __builtin_amdgcn_mfma_f32_16x16x32_f16(A0, B0, acc[0][0], 0, 0, 0); \
    acc[0][1] = __builtin_amdgcn_mfma_f32_16x16x32_f16(A0, B1, acc[0][1], 0, 0, 0); \
    acc[0][2] = __builtin_amdgcn_mfma_f32_16x16x32_f16(A0, B2, acc[0][2], 0, 0, 0); \
    acc[0][3] = __builtin_amdgcn_mfma_f32_16x16x32_f16(A0, B3, acc[0][3], 0, 0, 0); \
    acc[1][0] = __builtin_amdgcn_mfma_f32_16x16x32_f16(A1, B0, acc[1][0], 0, 0, 0); \
    acc[1][1] = __builtin_amdgcn_mfma_f32_16x16x32_f16(A1, B1, acc[1][1], 0, 0, 0); \
    acc[1][2] = __builtin_amdgcn_mfma_f32_16x16x32_f16(A1, B2, acc[1][2], 0, 0, 0); \
    acc[1][3] = __builtin_amdgcn_mfma_f32_16x16x32_f16(A1, B3, acc[1][3], 0, 0, 0); \
  } while (0)

  auto gemm_phase = [&](int q) {
    f16* Pb = Pl[q & 1];
    f32x4 acc[2][4] = {};
    f16x8 aE0, aE1, bE0, bE1, bE2, bE3;
    f16x8 aO0, aO1, bO0, bO1, bO2, bO3;
    LOADF(aE0, aE1, bE0, bE1, bE2, bE3, q, 0);
#pragma unroll
    for (int kt = 0; kt < 8; kt += 2) {
      LOADF(aO0, aO1, bO0, bO1, bO2, bO3, q, kt + 1);
      __builtin_amdgcn_s_setprio(1);
      MFMA8(aE0, aE1, bE0, bE1, bE2, bE3);
      __builtin_amdgcn_s_setprio(0);
      if (kt + 2 < 8) LOADF(aE0, aE1, bE0, bE1, bE2, bE3, q, kt + 2);
      __builtin_amdgcn_s_setprio(1);
      MFMA8(aO0, aO1, bO0, bO1, bO2, bO3);
      __builtin_amdgcn_s_setprio(0);
    }
#pragma unroll
    for (int mi = 0; mi < 2; ++mi) {
      int tl = mi * 16 + rbase;                  // 0..31
#pragma unroll
      for (int ni = 0; ni < 4; ++ni) {
        int hl = hh * 64 + ni * 16 + col;        // 0..127
        f16x4 v;
#pragma unroll
        for (int r = 0; r < 4; ++r) v[r] = (f16)acc[mi][ni][r];
        *(f16x4*)&Pb[w3 * 4096 + (tl >> 3) * 1024 + hl * 8 + (tl & 7)] = v;
      }
    }
  };

  if (wid < 6) gemm_phase(0);                    // prologue

  for (int p = 0; p < 16; ++p) {
    __syncthreads();                             // buf[p&1] ready; other free
    if (wid < 6) {
      if (p + 1 < 16) gemm_phase(p + 1);
    } else {
      const f16* Pr_ = &Pl[p & 1][c * 8];
      const f16* Pz_ = Pr_ + 4096;
      const f16* Ph_ = Pr_ + 8192;
      float* opm = out + ((size_t)b * 512 + p * 32) * 512 + hg;
#pragma unroll
      for (int g = 0; g < 4; ++g) {
        f16x8 R  = *(const f16x8*)(Pr_ + g * 1024);
        f16x8 Z  = *(const f16x8*)(Pz_ + g * 1024);
        f16x8 Hh = *(const f16x8*)(Ph_ + g * 1024);
#pragma unroll
        for (int j = 0; j < 8; ++j) {
          float prs = fmaf((float)R[j], 2.0f, br2);
          float pzs = fmaf((float)Z[j], -1.0f, nbz);
          float ph2 = (float)Hh[j] * 2.0f;
          float er = __expf(fmaf(h, mrc, prs));
          float rr = fmaf(-2.0f, rcpf(er + 1.0f), 2.0f);
          float ez = __expf(fmaf(h, mzc, pzs));
          float zz = rcpf(1.0f + ez);
          float ec = __expf(fmaf(rr, h + h, ph2));
          float cd = fmaf(-2.0f, rcpf(ec + 1.0f), 1.0f);
          h = fmaf(zz, h - cd, cd);
          __builtin_nontemporal_store(h, opm + (size_t)(g * 8 + j) * 512);
        }
      }
    }
  }
#undef LOADF
#undef MFMA8
}

// ---------------- launch ----------------
extern "C" void kernel_launch(void* const* d_in, const int* in_sizes, int n_in,
                              void* d_out, int out_size, void* d_ws, size_t ws_size,
                              hipStream_t stream) {
  const float* x  = (const float*)d_in[0];
  const float* h0 = (const float*)d_in[1];
  const float* kr = (const float*)d_in[2];
  const float* kz = (const float*)d_in[3];
  const float* kh = (const float*)d_in[4];
  const float* mr = (const float*)d_in[5];
  const float* mz = (const float*)d_in[6];
  const float* br = (const float*)d_in[7];
  const float* bz = (const float*)d_in[8];
  float* out = (float*)d_out;

  f16* Bf = (f16*)d_ws;                 // 393216 halfs = 786 KB
  f16* Xf = Bf + 393216;                // 16.8M halfs = 33.5 MB

  cvt_w<<<192, 256, 0, stream>>>(kr, kz, kh, Bf);
  cvt_x<<<8192, 256, 0, stream>>>(x, Xf);
  brc_fused<<<512, 512, 0, stream>>>(Xf, Bf, h0, mr, mz, br, bz, out);
}

// Round 14
// 138.652 us; speedup vs baseline: 1.0018x; 1.0018x over previous
//
#include <hip/hip_runtime.h>

typedef _Float16 f16;
typedef _Float16 f16x8 __attribute__((ext_vector_type(8)));
typedef _Float16 f16x4 __attribute__((ext_vector_type(4)));
typedef float f32x4 __attribute__((ext_vector_type(4)));

__device__ __forceinline__ float rcpf(float x) { return __builtin_amdgcn_rcpf(x); }

// ---------------- kernel 1: weight convert -> FRAGMENT-ORDERED layout ------
// Wt'[(nt*3+w)*8+kt][kq][ni][rl][8 halfs]
__global__ void __launch_bounds__(256) cvt_w(const float* __restrict__ Wr,
                                             const float* __restrict__ Wz,
                                             const float* __restrict__ Wh,
                                             f16* __restrict__ out) {
  int o = blockIdx.x * 256 + threadIdx.x;        // < 49152
  int rl = o & 15, ni = (o >> 4) & 3, kq = (o >> 6) & 3, kt = (o >> 8) & 7;
  int wnt = o >> 11;
  int w = wnt % 3, nt = wnt / 3;
  int n = nt * 64 + ni * 16 + rl;
  int k0 = kt * 32 + kq * 8;
  const float* W = (w == 0) ? Wr : ((w == 1) ? Wz : Wh);
  f16x8 v;
#pragma unroll
  for (int e = 0; e < 8; ++e) v[e] = (f16)W[(size_t)(k0 + e) * 512 + n];
  *(f16x8*)(out + (size_t)o * 8) = v;
}

// ---------------- kernel 2: x convert f32->f16, FRAGMENT-ORDERED -----------
// Xf'[m16*8+kt][kq][rl][8 halfs]
__global__ void __launch_bounds__(256) cvt_x(const float* __restrict__ in,
                                             f16* __restrict__ out) {
  int o = blockIdx.x * 256 + threadIdx.x;        // < 2097152
  int rl = o & 15, kq = (o >> 4) & 3, kt = (o >> 6) & 7, m16 = o >> 9;
  const float* src = in + (size_t)(m16 * 16 + rl) * 256 + kt * 32 + kq * 8;
  f16x8 v;
#pragma unroll
  for (int e = 0; e < 8; ++e) v[e] = (f16)src[e];
  *(f16x8*)(out + (size_t)o * 8) = v;
}

// ---------------- kernel 3: producer/consumer fused GEMM + scan ------------
// Block = (b, hs: 128-h slice), grid 512, 512 threads = 8 waves.
// Waves 0..5 (producers): register-streamed GEMM of t-tile 32 (phase p+1)
//   into LDS P buffer (p+1)&1, with kt-level double-buffered register
//   prefetch (even/odd named frag sets).
// Waves 6,7 (consumers): scan 32 t-steps of phase p from buffer p&1.
// One __syncthreads per phase; double-buffered P (49 KB) -> 2 blocks/CU.
// Occupancy PINNED at 4 waves/EU (2 blocks/CU) so the VGPR cap is 128 and
// the prefetch set (~90 VGPR) does NOT spill (R13: 64-VGPR squeeze spilled,
// +23 MB scratch writes).
__global__ void
__attribute__((amdgpu_flat_work_group_size(512, 512)))
__attribute__((amdgpu_waves_per_eu(4, 4)))
brc_fused(
    const f16* __restrict__ Af, const f16* __restrict__ Bf,
    const float* __restrict__ h0, const float* __restrict__ mr,
    const float* __restrict__ mz, const float* __restrict__ br,
    const float* __restrict__ bz, float* __restrict__ out) {
  __shared__ __align__(16) f16 Pl[2][12288];     // [buf][w3*4096+tg*1024+hl*8+t7]
  const int tid = threadIdx.x;
  const int wid = tid >> 6, lane = tid & 63;
  const int bid = blockIdx.x;
  const int lid = (bid & 7) * 64 + (bid >> 3);   // bijective XCD swizzle
  const int b = lid >> 2, hs = lid & 3;          // 4 hs-blocks of a b adjacent

  // ---- producer constants (waves 0..5) ----
  const int w3 = wid >> 1, hh = wid & 1;
  const int nt = hs * 2 + hh;
  const char* Ap = (const char*)Af + lane * 16;
  const char* Bp = (const char*)Bf + (lane >> 4) * 1024 + (lane & 15) * 16 +
                   (size_t)(nt * 3 + w3) * 32768;
  const int col = lane & 15, rbase = (lane >> 4) * 4;

  // ---- consumer state (waves 6,7): chain c = tid & 127 ----
  const int c = tid & 127;
  const int hg = hs * 128 + c;
  float h = h0[(size_t)b * 512 + hg];
  const float mrc = 2.0f * mr[hg], mzc = -mz[hg];
  const float br2 = 2.0f * br[hg], nbz = -bz[hg];

#define LOADF(A0, A1, B0, B1, B2, B3, q, kt)                                  \
  do {                                                                        \
    A0 = *(const f16x8*)(Ap + (size_t)((b * 32 + (q) * 2 + 0) * 8 + (kt)) * 1024); \
    A1 = *(const f16x8*)(Ap + (size_t)((b * 32 + (q) * 2 + 1) * 8 + (kt)) * 1024); \
    B0 = *(const f16x8*)(Bp + (size_t)(kt) * 4096 + 0 * 256);                 \
    B1 = *(const f16x8*)(Bp + (size_t)(kt) * 4096 + 1 * 256);                 \
    B2 = *(const f16x8*)(Bp + (size_t)(kt) * 4096 + 2 * 256);                 \
    B3 = *(const f16x8*)(Bp + (size_t)(kt) * 4096 + 3 * 256);                 \
  } while (0)

#define MFMA8(A0, A1, B0, B1, B2, B3)                                         \
  do {                                                                        \
    acc[0][0] = __builtin_amdgcn_mfma_f32_16x16x32_f16(A0, B0, acc[0][0], 0, 0, 0); \
    acc[0][1] = __builtin_amdgcn_mfma_f32_16x16x32_f16(A0, B1, acc[0][1], 0, 0, 0); \
    acc[0][2] = __builtin_amdgcn_mfma_f32_16x16x32_f16(A0, B2, acc[0][2], 0, 0, 0); \
    acc[0][3] = __builtin_amdgcn_mfma_f32_16x16x32_f16(A0, B3, acc[0][3], 0, 0, 0); \
    acc[1][0] = __builtin_amdgcn_mfma_f32_16x16x32_f16(A1, B0, acc[1][0], 0, 0, 0); \
    acc[1][1] = __builtin_amdgcn_mfma_f32_16x16x32_f16(A1, B1, acc[1][1], 0, 0, 0); \
    acc[1][2] = __builtin_amdgcn_mfma_f32_16x16x32_f16(A1, B2, acc[1][2], 0, 0, 0); \
    acc[1][3] = __builtin_amdgcn_mfma_f32_16x16x32_f16(A1, B3, acc[1][3], 0, 0, 0); \
  } while (0)

  auto gemm_phase = [&](int q) {
    f16* Pb = Pl[q & 1];
    f32x4 acc[2][4] = {};
    f16x8 aE0, aE1, bE0, bE1, bE2, bE3;
    f16x8 aO0, aO1, bO0, bO1, bO2, bO3;
    LOADF(aE0, aE1, bE0, bE1, bE2, bE3, q, 0);
#pragma unroll
    for (int kt = 0; kt < 8; kt += 2) {
      LOADF(aO0, aO1, bO0, bO1, bO2, bO3, q, kt + 1);
      __builtin_amdgcn_s_setprio(1);
      MFMA8(aE0, aE1, bE0, bE1, bE2, bE3);
      __builtin_amdgcn_s_setprio(0);
      if (kt + 2 < 8) LOADF(aE0, aE1, bE0, bE1, bE2, bE3, q, kt + 2);
      __builtin_amdgcn_s_setprio(1);
      MFMA8(aO0, aO1, bO0, bO1, bO2, bO3);
      __builtin_amdgcn_s_setprio(0);
    }
#pragma unroll
    for (int mi = 0; mi < 2; ++mi) {
      int tl = mi * 16 + rbase;                  // 0..31
#pragma unroll
      for (int ni = 0; ni < 4; ++ni) {
        int hl = hh * 64 + ni * 16 + col;        // 0..127
        f16x4 v;
#pragma unroll
        for (int r = 0; r < 4; ++r) v[r] = (f16)acc[mi][ni][r];
        *(f16x4*)&Pb[w3 * 4096 + (tl >> 3) * 1024 + hl * 8 + (tl & 7)] = v;
      }
    }
  };

  if (wid < 6) gemm_phase(0);                    // prologue

  for (int p = 0; p < 16; ++p) {
    __syncthreads();                             // buf[p&1] ready; other free
    if (wid < 6) {
      if (p + 1 < 16) gemm_phase(p + 1);
    } else {
      const f16* Pr_ = &Pl[p & 1][c * 8];
      const f16* Pz_ = Pr_ + 4096;
      const f16* Ph_ = Pr_ + 8192;
      float* opm = out + ((size_t)b * 512 + p * 32) * 512 + hg;
#pragma unroll
      for (int g = 0; g < 4; ++g) {
        f16x8 R  = *(const f16x8*)(Pr_ + g * 1024);
        f16x8 Z  = *(const f16x8*)(Pz_ + g * 1024);
        f16x8 Hh = *(const f16x8*)(Ph_ + g * 1024);
#pragma unroll
        for (int j = 0; j < 8; ++j) {
          float prs = fmaf((float)R[j], 2.0f, br2);
          float pzs = fmaf((float)Z[j], -1.0f, nbz);
          float ph2 = (float)Hh[j] * 2.0f;
          float er = __expf(fmaf(h, mrc, prs));
          float rr = fmaf(-2.0f, rcpf(er + 1.0f), 2.0f);
          float ez = __expf(fmaf(h, mzc, pzs));
          float zz = rcpf(1.0f + ez);
          float ec = __expf(fmaf(rr, h + h, ph2));
          float cd = fmaf(-2.0f, rcpf(ec + 1.0f), 1.0f);
          h = fmaf(zz, h - cd, cd);
          __builtin_nontemporal_store(h, opm + (size_t)(g * 8 + j) * 512);
        }
      }
    }
  }
#undef LOADF
#undef MFMA8
}

// ---------------- launch ----------------
extern "C" void kernel_launch(void* const* d_in, const int* in_sizes, int n_in,
                              void* d_out, int out_size, void* d_ws, size_t ws_size,
                              hipStream_t stream) {
  const float* x  = (const float*)d_in[0];
  const float* h0 = (const float*)d_in[1];
  const float* kr = (const float*)d_in[2];
  const float* kz = (const float*)d_in[3];
  const float* kh = (const float*)d_in[4];
  const float* mr = (const float*)d_in[5];
  const float* mz = (const float*)d_in[6];
  const float* br = (const float*)d_in[7];
  const float* bz = (const float*)d_in[8];
  float* out = (float*)d_out;

  f16* Bf = (f16*)d_ws;                 // 393216 halfs = 786 KB
  f16* Xf = Bf + 393216;                // 16.8M halfs = 33.5 MB

  cvt_w<<<192, 256, 0, stream>>>(kr, kz, kh, Bf);
  cvt_x<<<8192, 256, 0, stream>>>(x, Xf);
  brc_fused<<<512, 512, 0, stream>>>(Xf, Bf, h0, mr, mz, br, bz, out);
}

// Round 15
// 118.845 us; speedup vs baseline: 1.1688x; 1.1667x over previous
//
#include <hip/hip_runtime.h>

typedef _Float16 f16;
typedef _Float16 f16x8 __attribute__((ext_vector_type(8)));
typedef _Float16 f16x4 __attribute__((ext_vector_type(4)));
typedef float f32x4 __attribute__((ext_vector_type(4)));

__device__ __forceinline__ float rcpf(float x) { return __builtin_amdgcn_rcpf(x); }

// ---------------- kernel 1: weight convert -> FRAGMENT-ORDERED layout ------
// Wt'[(nt*3+w)*8+kt][kq][ni][rl][8 halfs]   (nt = 64-wide h tile, 0..7)
__global__ void __launch_bounds__(256) cvt_w(const float* __restrict__ Wr,
                                             const float* __restrict__ Wz,
                                             const float* __restrict__ Wh,
                                             f16* __restrict__ out) {
  int o = blockIdx.x * 256 + threadIdx.x;        // < 49152
  int rl = o & 15, ni = (o >> 4) & 3, kq = (o >> 6) & 3, kt = (o >> 8) & 7;
  int wnt = o >> 11;
  int w = wnt % 3, nt = wnt / 3;
  int n = nt * 64 + ni * 16 + rl;
  int k0 = kt * 32 + kq * 8;
  const float* W = (w == 0) ? Wr : ((w == 1) ? Wz : Wh);
  f16x8 v;
#pragma unroll
  for (int e = 0; e < 8; ++e) v[e] = (f16)W[(size_t)(k0 + e) * 512 + n];
  *(f16x8*)(out + (size_t)o * 8) = v;
}

// ---------------- kernel 2: x convert f32->f16, FRAGMENT-ORDERED -----------
// Xf'[m16*8+kt][kq][rl][8 halfs]
__global__ void __launch_bounds__(256) cvt_x(const float* __restrict__ in,
                                             f16* __restrict__ out) {
  int o = blockIdx.x * 256 + threadIdx.x;        // < 2097152
  int rl = o & 15, kq = (o >> 4) & 3, kt = (o >> 6) & 7, m16 = o >> 9;
  const float* src = in + (size_t)(m16 * 16 + rl) * 256 + kt * 32 + kq * 8;
  f16x8 v;
#pragma unroll
  for (int e = 0; e < 8; ++e) v[e] = (f16)src[e];
  *(f16x8*)(out + (size_t)o * 8) = v;
}

// ---------------- kernel 3: producer/consumer fused GEMM + scan ------------
// Block = (b, hs: 64-wide h slice), grid 1024 = 128b x 8hs, 256 thr = 4 waves.
// Waves 0..2 (producers): one WEIGHT each, tile 64t x 64h (Mf=4 x Nf=4,
//   acc[4][4]=64 VGPR, 8 loads / 16 MFMA = 0.5 KB/MFMA; the 3 waves load the
//   SAME A frags -> L1 dedupe). Phase q writes P into LDS buf q&1.
// Wave 3 (consumer): 64 chains, scans 64 t-steps of phase p from buf p&1.
// 8 phases, one __syncthreads each; P dbuf 48 KB -> 3 blocks/CU (12 waves).
// P never touches HBM. 256-thread shape: allocator historically grants
// ~90-110 VGPR here (R4/R10) unlike the 512-thread shape (R12-14 stuck at 64).
__global__ void __launch_bounds__(256) brc_fused(
    const f16* __restrict__ Af, const f16* __restrict__ Bf,
    const float* __restrict__ h0, const float* __restrict__ mr,
    const float* __restrict__ mz, const float* __restrict__ br,
    const float* __restrict__ bz, float* __restrict__ out) {
  __shared__ __align__(16) f16 Pl[2][12288];     // [buf][w*4096+tg*512+hl*8+t7]
  const int tid = threadIdx.x;
  const int wid = tid >> 6, lane = tid & 63;
  const int bid = blockIdx.x;
  const int lid = (bid & 7) * 128 + (bid >> 3);  // bijective XCD swizzle
  const int b = lid >> 3, hs = lid & 7;          // 8 hs-blocks of a b adjacent

  // ---- producer constants (waves 0..2): weight w3 = wid ----
  const int w3 = wid < 3 ? wid : 0;
  const char* Ap = (const char*)Af + lane * 16;
  const char* Bp = (const char*)Bf + (lane >> 4) * 1024 + (lane & 15) * 16 +
                   (size_t)(hs * 3 + w3) * 32768;
  const int col = lane & 15, rbase = (lane >> 4) * 4;

  // ---- consumer state (wave 3): chain = lane ----
  float h = 0.f, mrc = 0.f, mzc = 0.f, br2 = 0.f, nbz = 0.f;
  if (wid == 3) {
    int hg = hs * 64 + lane;
    h = h0[(size_t)b * 512 + hg];
    mrc = 2.0f * mr[hg]; mzc = -mz[hg];
    br2 = 2.0f * br[hg]; nbz = -bz[hg];
  }

  auto gemm_phase = [&](int q) {
    f16* Pb = Pl[q & 1];
    f32x4 acc[4][4] = {};
#pragma unroll
    for (int kt = 0; kt < 8; ++kt) {
      f16x8 a[4], bf[4];
#pragma unroll
      for (int mi = 0; mi < 4; ++mi)
        a[mi] = *(const f16x8*)(Ap +
                 (size_t)((b * 32 + q * 4 + mi) * 8 + kt) * 1024);
#pragma unroll
      for (int ni = 0; ni < 4; ++ni)
        bf[ni] = *(const f16x8*)(Bp + (size_t)kt * 4096 + ni * 256);
#pragma unroll
      for (int mi = 0; mi < 4; ++mi)
#pragma unroll
        for (int ni = 0; ni < 4; ++ni)
          acc[mi][ni] = __builtin_amdgcn_mfma_f32_16x16x32_f16(
              a[mi], bf[ni], acc[mi][ni], 0, 0, 0);
    }
#pragma unroll
    for (int mi = 0; mi < 4; ++mi) {
      int tl = mi * 16 + rbase;                  // 0..63
#pragma unroll
      for (int ni = 0; ni < 4; ++ni) {
        int hl = ni * 16 + col;                  // 0..63
        f16x4 v;
#pragma unroll
        for (int r = 0; r < 4; ++r) v[r] = (f16)acc[mi][ni][r];
        *(f16x4*)&Pb[w3 * 4096 + (tl >> 3) * 512 + hl * 8 + (tl & 7)] = v;
      }
    }
  };

  if (wid < 3) gemm_phase(0);                    // prologue

  for (int p = 0; p < 8; ++p) {
    __syncthreads();                             // buf[p&1] ready; other free
    if (wid < 3) {
      if (p + 1 < 8) gemm_phase(p + 1);
    } else {
      const f16* Pb = Pl[p & 1];
      float* opm = out + ((size_t)b * 512 + p * 64) * 512 + hs * 64 + lane;
#pragma unroll
      for (int tg = 0; tg < 8; ++tg) {
        f16x8 R  = *(const f16x8*)&Pb[tg * 512 + lane * 8];
        f16x8 Z  = *(const f16x8*)&Pb[4096 + tg * 512 + lane * 8];
        f16x8 Hh = *(const f16x8*)&Pb[8192 + tg * 512 + lane * 8];
#pragma unroll
        for (int j = 0; j < 8; ++j) {
          float prs = fmaf((float)R[j], 2.0f, br2);
          float pzs = fmaf((float)Z[j], -1.0f, nbz);
          float ph2 = (float)Hh[j] * 2.0f;
          float er = __expf(fmaf(h, mrc, prs));
          float rr = fmaf(-2.0f, rcpf(er + 1.0f), 2.0f);
          float ez = __expf(fmaf(h, mzc, pzs));
          float zz = rcpf(1.0f + ez);
          float ec = __expf(fmaf(rr, h + h, ph2));
          float cd = fmaf(-2.0f, rcpf(ec + 1.0f), 1.0f);
          h = fmaf(zz, h - cd, cd);
          __builtin_nontemporal_store(h, opm + (size_t)(tg * 8 + j) * 512);
        }
      }
    }
  }
}

// ---------------- launch ----------------
extern "C" void kernel_launch(void* const* d_in, const int* in_sizes, int n_in,
                              void* d_out, int out_size, void* d_ws, size_t ws_size,
                              hipStream_t stream) {
  const float* x  = (const float*)d_in[0];
  const float* h0 = (const float*)d_in[1];
  const float* kr = (const float*)d_in[2];
  const float* kz = (const float*)d_in[3];
  const float* kh = (const float*)d_in[4];
  const float* mr = (const float*)d_in[5];
  const float* mz = (const float*)d_in[6];
  const float* br = (const float*)d_in[7];
  const float* bz = (const float*)d_in[8];
  float* out = (float*)d_out;

  f16* Bf = (f16*)d_ws;                 // 393216 halfs = 786 KB
  f16* Xf = Bf + 393216;                // 16.8M halfs = 33.5 MB

  cvt_w<<<192, 256, 0, stream>>>(kr, kz, kh, Bf);
  cvt_x<<<8192, 256, 0, stream>>>(x, Xf);
  brc_fused<<<1024, 256, 0, stream>>>(Xf, Bf, h0, mr, mz, br, bz, out);
}